// Round 1
// baseline (238.755 us; speedup 1.0000x reference)
//
#include <hip/hip_runtime.h>

#define C_CH 16
#define DIM 48
#define HALF 24
#define P_TOT (48 * 48 * 48 * 48)  // 5308416
#define QSCALE (127.0f / 8.0f)
#define QINV   (8.0f / 127.0f)
#define NBUCK 4096                 // 8^4 Morton buckets

// shared coordinate math (identical everywhere)
__device__ __forceinline__ void coord_1d(float r, float mn, float mx, int& lo, int& hi,
                                         float& wlo, float& whi) {
    float t     = (r - mn) / (mx - mn);
    float ind   = t * 2.0f - 1.0f;
    float coord = (ind + 1.0f) * 0.5f * (float)(DIM - 1);
    float b  = floorf(coord);
    int   bi = (int)b;
    float w  = coord - b;
    bool v0 = (bi >= 0) && (bi < DIM);
    bool v1 = (bi + 1 >= 0) && (bi + 1 < DIM);
    lo  = min(max(bi, 0), DIM - 1);
    hi  = min(max(bi + 1, 0), DIM - 1);
    wlo = v0 ? (1.0f - w) : 0.0f;
    whi = v1 ? w : 0.0f;
}

__device__ __forceinline__ int q8(float x) {
    float q = rintf(x * QSCALE);
    q = fminf(fmaxf(q, -127.0f), 127.0f);
    return (int)q;
}

// 12-bit Morton key over 8x8x8x8 coarse cells (6 grid cells per bucket cell per dim)
__device__ __forceinline__ int ray_key(float4 r4, const float* ray_min, const float* ray_max) {
    float rr[4] = {r4.x, r4.y, r4.z, r4.w};
    int k[4];
#pragma unroll
    for (int d = 0; d < 4; ++d) {
        float t     = (rr[d] - ray_min[d]) / (ray_max[d] - ray_min[d]);
        float coord = t * (float)(DIM - 1);
        int bi = (int)floorf(coord);
        bi = min(max(bi, 0), DIM - 1);
        k[d] = bi / 6;  // 0..7
    }
    int m = 0;
#pragma unroll
    for (int b = 0; b < 3; ++b) {
        m |= ((k[0] >> b) & 1) << (4 * b + 3);
        m |= ((k[1] >> b) & 1) << (4 * b + 2);
        m |= ((k[2] >> b) & 1) << (4 * b + 1);
        m |= ((k[3] >> b) & 1) << (4 * b + 0);
    }
    return m;
}

// ---------------- convert: grid (C,P) f32 -> ws int8 tiled (line = 2x2x2 of y,z,w) ----------------
__global__ __launch_bounds__(256) void convert_tiled_kernel(
    const float* __restrict__ grid,
    uint4* __restrict__ ws)
{
    int t = blockIdx.x * 256 + threadIdx.x;
    if (t >= P_TOT) return;

    int intra = t & 7;
    int line  = t >> 3;
    int wh = line % HALF;  int r1 = line / HALF;
    int zh = r1 % HALF;    int r2 = r1 / HALF;
    int yh = r2 % HALF;    int x  = r2 / HALF;
    int wl = intra & 1, zl = (intra >> 1) & 1, yl = (intra >> 2) & 1;
    int y = yh * 2 + yl, z = zh * 2 + zl, w = wh * 2 + wl;
    int p = ((x * DIM + y) * DIM + z) * DIM + w;

    unsigned int pk[4];
#pragma unroll
    for (int j = 0; j < 4; ++j) {
        unsigned int b0 = (unsigned int)(q8(grid[(size_t)(4 * j + 0) * P_TOT + p]) & 0xFF);
        unsigned int b1 = (unsigned int)(q8(grid[(size_t)(4 * j + 1) * P_TOT + p]) & 0xFF);
        unsigned int b2 = (unsigned int)(q8(grid[(size_t)(4 * j + 2) * P_TOT + p]) & 0xFF);
        unsigned int b3 = (unsigned int)(q8(grid[(size_t)(4 * j + 3) * P_TOT + p]) & 0xFF);
        pk[j] = b0 | (b1 << 8) | (b2 << 16) | (b3 << 24);
    }
    ws[t] = make_uint4(pk[0], pk[1], pk[2], pk[3]);
}

// ---------------- counting sort: zero -> hist -> scan -> scatter ----------------
__global__ __launch_bounds__(256) void zero_kernel(int* __restrict__ p, int n) {
    int i = blockIdx.x * 256 + threadIdx.x;
    if (i < n) p[i] = 0;
}

__global__ __launch_bounds__(256) void hist_kernel(
    const float4* __restrict__ ray,
    const float* __restrict__ ray_min,
    const float* __restrict__ ray_max,
    int* __restrict__ keys,
    int* __restrict__ hist,
    int n_rays)
{
    int n = blockIdx.x * 256 + threadIdx.x;
    if (n >= n_rays) return;
    int key = ray_key(ray[n], ray_min, ray_max);
    keys[n] = key;
    atomicAdd(&hist[key], 1);
}

// single-block exclusive scan of NBUCK=4096 ints (1024 threads x 4)
__global__ __launch_bounds__(1024) void scan_kernel(
    const int* __restrict__ hist,
    int* __restrict__ offs)
{
    __shared__ int s[1024];
    int t = threadIdx.x;
    int4 h = ((const int4*)hist)[t];
    int sum = h.x + h.y + h.z + h.w;
    s[t] = sum;
    __syncthreads();
#pragma unroll
    for (int off = 1; off < 1024; off <<= 1) {
        int v = (t >= off) ? s[t - off] : 0;
        __syncthreads();
        s[t] += v;
        __syncthreads();
    }
    int base = s[t] - sum;  // exclusive prefix
    int4 o;
    o.x = base;
    o.y = base + h.x;
    o.z = base + h.x + h.y;
    o.w = base + h.x + h.y + h.z;
    ((int4*)offs)[t] = o;
}

__global__ __launch_bounds__(256) void scatter_kernel(
    const float4* __restrict__ ray,
    const int* __restrict__ keys,
    int* __restrict__ offs,
    float4* __restrict__ rs,
    int* __restrict__ rid,
    int n_rays)
{
    int n = blockIdx.x * 256 + threadIdx.x;
    if (n >= n_rays) return;
    int key = keys[n];
    int pos = atomicAdd(&offs[key], 1);
    rs[pos]  = ray[n];
    rid[pos] = n;
}

// ---------------- gather: 16 corner-cells, one dwordx4 each, tiled int8 ----------------
__device__ __forceinline__ void accum_cell(const uint4& cell, float wc, float* acc) {
#pragma unroll
    for (int j = 0; j < 4; ++j) {
        unsigned int u = (&cell.x)[j];
        acc[4 * j + 0] += (float)((int)(u << 24) >> 24) * wc;
        acc[4 * j + 1] += (float)((int)(u << 16) >> 24) * wc;
        acc[4 * j + 2] += (float)((int)(u <<  8) >> 24) * wc;
        acc[4 * j + 3] += (float)((int)u         >> 24) * wc;
    }
}

__device__ __forceinline__ void gather_body(
    float4 r4, const uint4* __restrict__ gq,
    const float* __restrict__ ray_min, const float* __restrict__ ray_max,
    float* acc)
{
    float rr[4] = {r4.x, r4.y, r4.z, r4.w};
    int   i0[4], i1[4];
    float w0[4], w1[4];
#pragma unroll
    for (int d = 0; d < 4; ++d)
        coord_1d(rr[d], ray_min[d], ray_max[d], i0[d], i1[d], w0[d], w1[d]);

#pragma unroll
    for (int c = 0; c < C_CH; ++c) acc[c] = 0.0f;

#pragma unroll
    for (int cx = 0; cx < 2; ++cx) {
        int   x  = cx ? i1[0] : i0[0];
        float fx = (cx ? w1[0] : w0[0]) * QINV;  // fold int8 scale into weight
        int bx = x * HALF;
#pragma unroll
        for (int cy = 0; cy < 2; ++cy) {
            int   y   = cy ? i1[1] : i0[1];
            float fxy = fx * (cy ? w1[1] : w0[1]);
            int ly = (bx + (y >> 1)) * HALF;
            int iy = (y & 1) << 2;
#pragma unroll
            for (int cz = 0; cz < 2; ++cz) {
                int   z    = cz ? i1[2] : i0[2];
                float fxyz = fxy * (cz ? w1[2] : w0[2]);
                int lz = (ly + (z >> 1)) * HALF;
                int iz = iy | ((z & 1) << 1);
#pragma unroll
                for (int cw = 0; cw < 2; ++cw) {
                    int   w  = cw ? i1[3] : i0[3];
                    float wc = fxyz * (cw ? w1[3] : w0[3]);
                    int cellidx = ((lz + (w >> 1)) << 3) | iz | (w & 1);
                    uint4 cell = gq[cellidx];
                    accum_cell(cell, wc, acc);
                }
            }
        }
    }
}

__global__ __launch_bounds__(256) void gather_sorted_kernel(
    const float4* __restrict__ rs,
    const int* __restrict__ rid,
    const uint4* __restrict__ gq,
    const float* __restrict__ ray_min,
    const float* __restrict__ ray_max,
    float* __restrict__ out,
    int n_rays)
{
    // XCD-chunked swizzle: each XCD gets a contiguous chunk of the sorted ray order
    int bid = (int)blockIdx.x;
    int nb  = (int)gridDim.x;
    if ((nb & 7) == 0) {
        int xcd = bid & 7, chunk = bid >> 3;
        bid = xcd * (nb >> 3) + chunk;
    }
    int n = bid * 256 + (int)threadIdx.x;
    if (n >= n_rays) return;

    float acc[C_CH];
    gather_body(rs[n], gq, ray_min, ray_max, acc);

    int outn = rid[n];
    float4* o = reinterpret_cast<float4*>(out + (size_t)outn * C_CH);
    o[0] = make_float4(acc[0],  acc[1],  acc[2],  acc[3]);
    o[1] = make_float4(acc[4],  acc[5],  acc[6],  acc[7]);
    o[2] = make_float4(acc[8],  acc[9],  acc[10], acc[11]);
    o[3] = make_float4(acc[12], acc[13], acc[14], acc[15]);
}

// unsorted mid-fallback (ws fits grid but not sort buffers)
__global__ __launch_bounds__(256) void gather_tiled_kernel(
    const float4* __restrict__ ray,
    const uint4* __restrict__ gq,
    const float* __restrict__ ray_min,
    const float* __restrict__ ray_max,
    float* __restrict__ out,
    int n_rays)
{
    int n = blockIdx.x * 256 + threadIdx.x;
    if (n >= n_rays) return;
    float acc[C_CH];
    gather_body(ray[n], gq, ray_min, ray_max, acc);
    float4* o = reinterpret_cast<float4*>(out + (size_t)n * C_CH);
    o[0] = make_float4(acc[0],  acc[1],  acc[2],  acc[3]);
    o[1] = make_float4(acc[4],  acc[5],  acc[6],  acc[7]);
    o[2] = make_float4(acc[8],  acc[9],  acc[10], acc[11]);
    o[3] = make_float4(acc[12], acc[13], acc[14], acc[15]);
}

// ---------------- f32 fallback if ws too small ----------------
__global__ __launch_bounds__(256) void lf4d_gather_kernel(
    const float4* __restrict__ ray,
    const float* __restrict__ grid,
    const float* __restrict__ ray_min,
    const float* __restrict__ ray_max,
    float* __restrict__ out,
    int n_rays)
{
    int n = blockIdx.x * 256 + threadIdx.x;
    if (n >= n_rays) return;
    float4 r4 = ray[n];
    float rr[4] = {r4.x, r4.y, r4.z, r4.w};
    int   i0[4], i1[4];
    float w0[4], w1[4];
#pragma unroll
    for (int d = 0; d < 4; ++d)
        coord_1d(rr[d], ray_min[d], ray_max[d], i0[d], i1[d], w0[d], w1[d]);
    float acc[C_CH];
#pragma unroll
    for (int c = 0; c < C_CH; ++c) acc[c] = 0.0f;
    const int s0 = DIM * DIM * DIM, s1 = DIM * DIM, s2 = DIM;
#pragma unroll
    for (int k = 0; k < 8; ++k) {
        int   x  = (k & 1) ? i1[0] : i0[0];
        float wx = (k & 1) ? w1[0] : w0[0];
        int   y  = (k & 2) ? i1[1] : i0[1];
        float wy = (k & 2) ? w1[1] : w0[1];
        int   z  = (k & 4) ? i1[2] : i0[2];
        float wz = (k & 4) ? w1[2] : w0[2];
        int   base = x * s0 + y * s1 + z * s2;
        float wxyz = wx * wy * wz;
        float wa = wxyz * w0[3], wb = wxyz * w1[3];
        int ia = base + i0[3], ib = base + i1[3];
#pragma unroll
        for (int c = 0; c < C_CH; ++c) {
            float va = grid[c * P_TOT + ia];
            float vb = grid[c * P_TOT + ib];
            acc[c] += va * wa + vb * wb;
        }
    }
    float4* o = reinterpret_cast<float4*>(out + (size_t)n * C_CH);
    o[0] = make_float4(acc[0],  acc[1],  acc[2],  acc[3]);
    o[1] = make_float4(acc[4],  acc[5],  acc[6],  acc[7]);
    o[2] = make_float4(acc[8],  acc[9],  acc[10], acc[11]);
    o[3] = make_float4(acc[12], acc[13], acc[14], acc[15]);
}

static inline size_t align256(size_t x) { return (x + 255) & ~(size_t)255; }

extern "C" void kernel_launch(void* const* d_in, const int* in_sizes, int n_in,
                              void* d_out, int out_size, void* d_ws, size_t ws_size,
                              hipStream_t stream) {
    const float4* ray     = (const float4*)d_in[0];
    const float*  grid    = (const float*)d_in[1];
    const float*  ray_min = (const float*)d_in[2];
    const float*  ray_max = (const float*)d_in[3];
    float*        out     = (float*)d_out;

    int n_rays  = in_sizes[0] / 4;
    int rblocks = (n_rays + 255) / 256;
    int tblocks = (P_TOT + 255) / 256;

    // workspace layout
    size_t grid_bytes = (size_t)P_TOT * 16;                         // int8 tiled grid, ~81 MiB
    size_t rs_off   = align256(grid_bytes);                         // sorted rays, float4
    size_t rid_off  = align256(rs_off  + (size_t)n_rays * 16);      // original indices
    size_t keys_off = align256(rid_off + (size_t)n_rays * 4);       // bucket keys
    size_t hist_off = align256(keys_off + (size_t)n_rays * 4);      // histogram
    size_t offs_off = align256(hist_off + (size_t)NBUCK * 4);       // scanned offsets
    size_t need_full = offs_off + (size_t)NBUCK * 4;

    if (ws_size >= need_full) {
        char*   w    = (char*)d_ws;
        uint4*  gq   = (uint4*)w;
        float4* rs   = (float4*)(w + rs_off);
        int*    rid  = (int*)(w + rid_off);
        int*    keys = (int*)(w + keys_off);
        int*    hist = (int*)(w + hist_off);
        int*    offs = (int*)(w + offs_off);

        convert_tiled_kernel<<<tblocks, 256, 0, stream>>>(grid, gq);
        zero_kernel<<<(NBUCK + 255) / 256, 256, 0, stream>>>(hist, NBUCK);
        hist_kernel<<<rblocks, 256, 0, stream>>>(ray, ray_min, ray_max, keys, hist, n_rays);
        scan_kernel<<<1, 1024, 0, stream>>>(hist, offs);
        scatter_kernel<<<rblocks, 256, 0, stream>>>(ray, keys, offs, rs, rid, n_rays);
        gather_sorted_kernel<<<rblocks, 256, 0, stream>>>(
            rs, rid, (const uint4*)gq, ray_min, ray_max, out, n_rays);
    } else if (ws_size >= grid_bytes) {
        uint4* gq = (uint4*)d_ws;
        convert_tiled_kernel<<<tblocks, 256, 0, stream>>>(grid, gq);
        gather_tiled_kernel<<<rblocks, 256, 0, stream>>>(
            ray, (const uint4*)gq, ray_min, ray_max, out, n_rays);
    } else {
        lf4d_gather_kernel<<<rblocks, 256, 0, stream>>>(ray, grid, ray_min, ray_max, out, n_rays);
    }
}